// Round 27
// baseline (59.594 us; speedup 1.0000x reference)
//
#include <hip/hip_runtime.h>
#include <math.h>

// CasperNet R27: B=131072, D=256, H=64, O=10.
// R26 failed at absmax 0.125: bo was added TWICE (k1 staged it into head
// cols AND k2 added it at the store). R27 = R26 with the fix: k1 stages
// bias only for hidden cols (n<64); k2 adds bo once. Structure unchanged:
//  k1: phase-1 GEMM + bh ONLY -> C-frags stored f32x4 to blocked layout
//      ws[(rowblk64*80+col)*64+row64]; pure stream, no 2nd barrier.
//  k2: one ROW PER LANE; a[74] in regs; coalesced 256B/wave loads; full
//      74-wide f32 triangular cascade; weights from 20KB LDS table
//      (pre-masked zeros -> full-quad fmas exact); zero cross-lane ops.
// Math: bf16 GEMM (unchanged) + f32 cascade (higher precision than the
// R16-R25 bf16 rank-16 path) -> expect absmax 0.015625-0.03125.

#define DIMD 256
#define DIMH 64
#define DIMO 10
#define DT   320
#define NT   5        // 5 n-tiles of 16 = 80 cols (74 used)
#define TM   128      // k1 rows per block: 8 waves x 16
#define BLK1 512
#define BLK2 256

typedef __attribute__((ext_vector_type(4))) float f32x4;
typedef __attribute__((ext_vector_type(8))) short bf16x8;

__device__ inline unsigned short f2bf(float f) {   // RNE, deterministic
    union { float f; unsigned u; } v; v.f = f;
    unsigned r = v.u + 0x7FFFu + ((v.u >> 16) & 1u);
    return (unsigned short)(r >> 16);
}
__device__ inline float sigm(float s) {
    return __builtin_amdgcn_rcpf(1.0f + __expf(-s));   // v_rcp_f32
}

// ================= k1: streaming GEMM, C-frags -> blocked ws =============
__global__ __launch_bounds__(BLK1, 2) void casper_k1(
    const float* __restrict__ x,    // [B, 256]
    const float* __restrict__ Wh,   // [64, 320]
    const float* __restrict__ bh,   // [64]
    const float* __restrict__ Wo,   // [10, 320]
    float* __restrict__ wsi,        // [B/64][80][64] f32 intermediate
    int B)
{
    __shared__ short sW[80 * DIMD];     // bf16 [n][k], swizzled; 40960B

    const int tid = threadIdx.x;

    // ---- stage W1 = [Wh_x; Wo_x] as bf16, swizzled (rows 74-79 zero) ----
    for (int idx = tid; idx < 80 * 64; idx += BLK1) {    // 80 rows x 64 float4
        const int n = idx >> 6, k0 = (idx & 63) * 4;
        float4 v = make_float4(0.f, 0.f, 0.f, 0.f);
        if (n < DIMH)      v = *reinterpret_cast<const float4*>(Wh + n * DT + k0);
        else if (n < 74)   v = *reinterpret_cast<const float4*>(Wo + (n - 64) * DT + k0);
        const int kz = k0 ^ ((n & 7) << 3);
        short4 sv;
        sv.x = (short)f2bf(v.x); sv.y = (short)f2bf(v.y);
        sv.z = (short)f2bf(v.z); sv.w = (short)f2bf(v.w);
        *reinterpret_cast<short4*>(sW + n * DIMD + kz) = sv;   // 8B aligned
    }
    __syncthreads();

    const int l  = tid & 63;
    const int w  = tid >> 6;            // wave 0..7 -> rows w*16..w*16+15
    const int lm = l & 15, lg = l >> 4;

    // ---- phase 1: one 16-row tile per wave ----
    const size_t rowA = (size_t)blockIdx.x * TM + w * 16 + lm;
    const float* xr = x + rowA * DIMD + lg * 8;

    f32x4 acc[NT];
    #pragma unroll
    for (int t = 0; t < NT; ++t) acc[t] = (f32x4){0.f, 0.f, 0.f, 0.f};

    #pragma unroll
    for (int ks = 0; ks < 8; ++ks) {
        const float4 xa = *reinterpret_cast<const float4*>(xr + ks * 32);
        const float4 xb = *reinterpret_cast<const float4*>(xr + ks * 32 + 4);
        bf16x8 af;
        af[0] = (short)f2bf(xa.x); af[1] = (short)f2bf(xa.y);
        af[2] = (short)f2bf(xa.z); af[3] = (short)f2bf(xa.w);
        af[4] = (short)f2bf(xb.x); af[5] = (short)f2bf(xb.y);
        af[6] = (short)f2bf(xb.z); af[7] = (short)f2bf(xb.w);
        #pragma unroll
        for (int t = 0; t < NT; ++t) {
            const int n = t * 16 + lm;
            const int kz = (lg * 8 + ks * 32) ^ ((n & 7) << 3);
            const bf16x8 bf = *reinterpret_cast<const bf16x8*>(sW + n * DIMD + kz);
            acc[t] = __builtin_amdgcn_mfma_f32_16x16x32_bf16(af, bf, acc[t], 0, 0, 0);
        }
    }
    // bias: HIDDEN neurons only (head bias bo is added once, in k2)
    #pragma unroll
    for (int t = 0; t < NT; ++t) {
        const int n = t * 16 + lm;
        const float bt = (n < DIMH) ? bh[n] : 0.f;
        acc[t][0] += bt; acc[t][1] += bt; acc[t][2] += bt; acc[t][3] += bt;
    }

    // ---- store C-frags directly to blocked layout (5 f32x4 per lane) ----
    const size_t rowblk = (size_t)blockIdx.x * 2 + (w >> 2);
    const int r64 = ((w & 3) << 4) + (lg << 2);   // (w%4)*16 + lg*4
    #pragma unroll
    for (int t = 0; t < NT; ++t) {
        float* dst = wsi + (rowblk * 80 + t * 16 + lm) * 64 + r64;
        *reinterpret_cast<f32x4*>(dst) = acc[t];
    }
}

// ================= k2: lane-local f32 cascade =============================
__global__ __launch_bounds__(BLK2, 2) void casper_k2(
    const float* __restrict__ wsi,  // [B/64][80][64] f32 intermediate
    const float* __restrict__ Wh,   // [64, 320]
    const float* __restrict__ Wo,   // [10, 320]
    const float* __restrict__ bo,   // [10]
    float* __restrict__ out,        // [B, 10]
    int B)
{
    __shared__ float sUt[DIMH * 80];    // [i][j]: masked U/head; 20480B

    const int tid = threadIdx.x;

    // ---- stage cascade weight table (pre-masked; L2-hot scattered) ----
    for (int idx = tid; idx < DIMH * 80; idx += BLK2) {
        const int i = idx / 80, j = idx - i * 80;
        float v = 0.f;
        if (j < DIMH)       { if (j > i) v = Wh[j * DT + DIMD + i]; }
        else if (j < 74)    v = Wo[(j - DIMH) * DT + DIMD + i];
        sUt[idx] = v;
    }
    __syncthreads();

    const int l  = tid & 63;
    const int w2 = tid >> 6;            // wave 0..3, 64 rows each
    const size_t rowblk = (size_t)blockIdx.x * 4 + w2;

    // ---- load this lane's row: 74 coalesced dwords (256B/wave each) ----
    const float* src = wsi + rowblk * 80 * 64 + l;
    float a[74];
    #pragma unroll
    for (int c = 0; c < 74; ++c) a[c] = src[c * 64];

    // ---- full 74-wide triangular cascade, all f32, lane-local ----
    #pragma unroll
    for (int i = 0; i < DIMH; ++i) {
        const float h = sigm(a[i]);
        const float* uw = sUt + i * 80;
        const int q0 = (i + 1) >> 2;    // first quad containing j>i
        #pragma unroll
        for (int q = q0; q < 18; ++q) { // quads cover j=0..71; j<=i are 0
            const f32x4 u4 = *reinterpret_cast<const f32x4*>(uw + q * 4);
            a[q * 4 + 0] = fmaf(u4[0], h, a[q * 4 + 0]);
            a[q * 4 + 1] = fmaf(u4[1], h, a[q * 4 + 1]);
            a[q * 4 + 2] = fmaf(u4[2], h, a[q * 4 + 2]);
            a[q * 4 + 3] = fmaf(u4[3], h, a[q * 4 + 3]);
        }
        // tail j=72,73 (always > i for i<64)
        const float2 ut = *reinterpret_cast<const float2*>(uw + 72);
        a[72] = fmaf(ut.x, h, a[72]);
        a[73] = fmaf(ut.y, h, a[73]);
    }

    // ---- store outputs (+bo, added exactly once), 5 x float2 ----
    const size_t row = rowblk * 64 + l;
    float* orow = out + row * DIMO;
    #pragma unroll
    for (int c = 0; c < 5; ++c) {
        const float2 v = make_float2(a[64 + 2 * c] + bo[2 * c],
                                     a[65 + 2 * c] + bo[2 * c + 1]);
        *reinterpret_cast<float2*>(orow + 2 * c) = v;
    }
}

extern "C" void kernel_launch(void* const* d_in, const int* in_sizes, int n_in,
                              void* d_out, int out_size, void* d_ws, size_t ws_size,
                              hipStream_t stream) {
    const float* x  = (const float*)d_in[0];
    const float* Wh = (const float*)d_in[1];
    const float* bh = (const float*)d_in[2];
    const float* Wo = (const float*)d_in[3];
    const float* bo = (const float*)d_in[4];
    float* out = (float*)d_out;
    float* wsi = (float*)d_ws;             // B/64*80*64*4 = 41.9 MB

    const int B = in_sizes[0] / DIMD;      // 131072

    hipLaunchKernelGGL(casper_k1, dim3(B / TM), dim3(BLK1), 0, stream,
                       x, Wh, bh, Wo, wsi, B);
    hipLaunchKernelGGL(casper_k2, dim3(B / 256), dim3(BLK2), 0, stream,
                       wsi, Wh, Wo, bo, out, B);
}